// Round 1
// 473.052 us; speedup vs baseline: 1.0102x; 1.0102x over previous
//
#include <hip/hip_runtime.h>
#include <stdint.h>

#define DM 768
#define VOC 32128
#define NTOK 2048
#define NBY (VOC / 128)   // 251 vocab tiles
#define IGN (-100)

typedef __bf16 bf16x8 __attribute__((ext_vector_type(8)));
typedef float f32x4 __attribute__((ext_vector_type(4)));

typedef __attribute__((address_space(1))) void gvoid_t;
typedef __attribute__((address_space(3))) void svoid_t;

__device__ __forceinline__ void gl_lds16(const void* g, void* s) {
  // 16B per lane; LDS dest = wave-uniform base + lane*16 (linear)
  __builtin_amdgcn_global_load_lds((gvoid_t*)g, (svoid_t*)s, 16, 0, 0);
}

__device__ __forceinline__ unsigned short f2bf(float f) {
  unsigned int u = __float_as_uint(f);
  u = (u + 0x7fffu + ((u >> 16) & 1u)) >> 16;  // RNE
  return (unsigned short)u;
}

// ---------------- W fp32 -> bf16 ----------------
__global__ void __launch_bounds__(256) cvt_w_kernel(const float* __restrict__ W,
                                                    unsigned short* __restrict__ Wb) {
  size_t i = ((size_t)blockIdx.x * 256 + threadIdx.x) * 4;
  float4 v = *(const float4*)(W + i);
  ushort4 o;
  o.x = f2bf(v.x); o.y = f2bf(v.y); o.z = f2bf(v.z); o.w = f2bf(v.w);
  *(ushort4*)(Wb + i) = o;
}

// ---------------- RMSNorm -> bf16 ----------------
__global__ void __launch_bounds__(256) rmsnorm_kernel(const float* __restrict__ x,
                                                      const float* __restrict__ w,
                                                      unsigned short* __restrict__ h) {
  int tok = blockIdx.x;
  const float* xr = x + (size_t)tok * DM;
  int t = threadIdx.x;
  float v0 = xr[t], v1 = xr[t + 256], v2 = xr[t + 512];
  float ss = v0 * v0 + v1 * v1 + v2 * v2;
  for (int off = 32; off; off >>= 1) ss += __shfl_down(ss, off);
  __shared__ float red[4];
  int wv = t >> 6, ln = t & 63;
  if (ln == 0) red[wv] = ss;
  __syncthreads();
  float tot = red[0] + red[1] + red[2] + red[3];
  float inv = rsqrtf(tot * (1.0f / DM) + 1e-6f);
  unsigned short* hr = h + (size_t)tok * DM;
  hr[t]       = f2bf(v0 * inv * w[t]);
  hr[t + 256] = f2bf(v1 * inv * w[t + 256]);
  hr[t + 512] = f2bf(v2 * inv * w[t + 512]);
}

// ---------------- GEMM + fused CE partials ----------------
// Tile 256(tok) x 128(voc), BK=64, 8 waves (512 thr), per-wave 64x64 (acc 4x4).
// Triple-buffered LDS (3 x 48KB = 144KB, 1 block/CU) with counted vmcnt:
//   loop t: STAGE(t+2) ; COMPUTE(t) ; s_waitcnt vmcnt(6) ; s_barrier
// vmcnt retires in order -> vmcnt(6) guarantees tile t+1's 6 loads landed while
// tile t+2's 6 ride across the barrier (T3+T4). Never vmcnt(0) in the loop.
//
// LDS swizzle (rule #21 both-sides): element (row r, k-slot q of 8x16B slots)
// stored at slot q ^ (r&7). gl_lds dest stays linear; the SOURCE col is
// pre-swizzled per-lane: q_g = (lane&7) ^ (lane>>3). Read side applies the
// same XOR -> uniform 8 lanes per bank for ds_read_b128 (conflict-free).
#define TILE_ELEMS 24576   // A 256x64 + B 128x64 bf16
#define A_ELEMS    16384

__global__ void __launch_bounds__(512, 2) gemm_kernel(const unsigned short* __restrict__ A,
                                                      const unsigned short* __restrict__ Bw,
                                                      float* __restrict__ C,
                                                      float* __restrict__ Pm,
                                                      float* __restrict__ Ps) {
  __shared__ __align__(16) unsigned short LDS[3 * TILE_ELEMS];

  // XCD-grouping remap: grid = 2008 = 8*251 ids. XCD x (= id%8) gets the
  // contiguous work range w in [251*x, 251*(x+1)); by-groups of 8 token-blocks
  // (sharing one 192KB W panel) stay on one XCD -> W fetched ~once from HBM.
  const int id = blockIdx.x;
  const int w  = (id & 7) * 251 + (id >> 3);   // bijective for 2008 blocks
  const int by = w >> 3;                       // 0..250 vocab tile
  const int m0 = (w & 7) * 256;                // token offset
  const int n0 = by * 128;                     // vocab offset

  const int tid  = threadIdx.x;
  const int wv   = tid >> 6, ln = tid & 63;
  const int l15  = ln & 15, quad = ln >> 4;
  const int wvm  = wv >> 1;                    // 0..3 -> 64-row slice
  const int wvn  = wv & 1;                     // 0..1 -> 64-col slice

  // --- staging addresses (pre-swizzled global source, linear LDS dest) ---
  const int lr  = ln >> 3;                     // row within 8-row chunk
  const int qsw = ((ln & 7) ^ lr) * 8;         // pre-swizzled source k-slot
  const unsigned short* aS = A  + (size_t)(m0 + wv * 32 + lr) * DM + qsw;
  const unsigned short* bS = Bw + (size_t)(n0 + wv * 16 + lr) * DM + qsw;
  const int aDof = wv * 32 * 64;               // wave stages A rows [wv*32, +32)
  const int bDof = A_ELEMS + wv * 16 * 64;     // wave stages B rows [wv*16, +16)

  auto STAGE = [&](unsigned short* sb, int kt) {
    const unsigned short* a = aS + kt * 64;
    const unsigned short* b = bS + kt * 64;
    unsigned short* ad = sb + aDof;
    unsigned short* bd = sb + bDof;
#pragma unroll
    for (int c = 0; c < 4; ++c) gl_lds16(a + (size_t)c * (8 * DM), ad + c * 512);
#pragma unroll
    for (int c = 0; c < 2; ++c) gl_lds16(b + (size_t)c * (8 * DM), bd + c * 512);
  };

  f32x4 acc[4][4];
#pragma unroll
  for (int i = 0; i < 4; ++i)
#pragma unroll
    for (int j = 0; j < 4; ++j) {
      acc[i][j][0] = 0.f; acc[i][j][1] = 0.f; acc[i][j][2] = 0.f; acc[i][j][3] = 0.f;
    }

  const int sw = l15 & 7;
  auto COMPUTE = [&](const unsigned short* At) {
    const unsigned short* Bt = At + A_ELEMS;
#pragma unroll
    for (int kk = 0; kk < 2; ++kk) {
      const int so = ((kk * 4 + quad) ^ sw) * 8;   // swizzled read slot
      bf16x8 a[4], b[4];
#pragma unroll
      for (int i = 0; i < 4; ++i) {
        a[i] = *(const bf16x8*)(At + (wvm * 64 + i * 16 + l15) * 64 + so);
        b[i] = *(const bf16x8*)(Bt + (wvn * 64 + i * 16 + l15) * 64 + so);
      }
      __builtin_amdgcn_s_setprio(1);
#pragma unroll
      for (int mi = 0; mi < 4; ++mi)
#pragma unroll
        for (int ni = 0; ni < 4; ++ni)
          acc[mi][ni] = __builtin_amdgcn_mfma_f32_16x16x32_bf16(a[mi], b[ni], acc[mi][ni], 0, 0, 0);
      __builtin_amdgcn_s_setprio(0);
    }
  };

  unsigned short* p0 = LDS;
  unsigned short* p1 = LDS + TILE_ELEMS;
  unsigned short* p2 = LDS + 2 * TILE_ELEMS;

  // prologue: 2 tiles in flight, wait only the first
  STAGE(p0, 0);
  STAGE(p1, 1);
  asm volatile("s_waitcnt vmcnt(6)" ::: "memory");
  __builtin_amdgcn_s_barrier();

  for (int t = 0; t < 10; ++t) {               // K = 768 -> 12 tiles of BK=64
    STAGE(p2, t + 2);
    COMPUTE(p0);
    asm volatile("s_waitcnt vmcnt(6)" ::: "memory");   // tile t+1 done; t+2 in flight
    __builtin_amdgcn_s_barrier();
    unsigned short* tmp = p0; p0 = p1; p1 = p2; p2 = tmp;
  }
  COMPUTE(p0);                                 // tile 10
  asm volatile("s_waitcnt vmcnt(0)" ::: "memory");     // drain tile 11
  __builtin_amdgcn_s_barrier();
  COMPUTE(p1);                                 // tile 11

  // ---- Epilogue 1: non-temporal score stores.
  // C/D layout: col = l15 (+ni*16), row = quad*4 + r (+mi*16).
#pragma unroll
  for (int mi = 0; mi < 4; ++mi) {
#pragma unroll
    for (int r = 0; r < 4; ++r) {
      const int row = m0 + wvm * 64 + mi * 16 + quad * 4 + r;
      float* cp = C + (size_t)row * VOC + (n0 + wvn * 64 + l15);
#pragma unroll
      for (int ni = 0; ni < 4; ++ni)
        __builtin_nontemporal_store(acc[mi][ni][r], cp + ni * 16);
    }
  }

  // ---- Epilogue 2: per-row (max, sumexp) partials over this block's 128 cols.
  // Wave covers 64 rows x 64 cols; shfl_xor 1,2,4,8 reduces inside quad group.
  float* pmL = (float*)LDS;        // [2][256] — buf0 region, last read at t=9
  float* psL = pmL + 512;          // [2][256]
  float rm[4][4], rs[4][4];
#pragma unroll
  for (int mi = 0; mi < 4; ++mi) {
#pragma unroll
    for (int r = 0; r < 4; ++r) {
      float m = fmaxf(fmaxf(acc[mi][0][r], acc[mi][1][r]),
                      fmaxf(acc[mi][2][r], acc[mi][3][r]));
#pragma unroll
      for (int off = 1; off < 16; off <<= 1) m = fmaxf(m, __shfl_xor(m, off));
      float s = __expf(acc[mi][0][r] - m) + __expf(acc[mi][1][r] - m) +
                __expf(acc[mi][2][r] - m) + __expf(acc[mi][3][r] - m);
#pragma unroll
      for (int off = 1; off < 16; off <<= 1) s += __shfl_xor(s, off);
      rm[mi][r] = m; rs[mi][r] = s;
    }
  }
  if (l15 == 0) {
#pragma unroll
    for (int mi = 0; mi < 4; ++mi)
#pragma unroll
      for (int r = 0; r < 4; ++r) {
        int rr = wvm * 64 + mi * 16 + quad * 4 + r;    // 0..255
        pmL[wvn * 256 + rr] = rm[mi][r];
        psL[wvn * 256 + rr] = rs[mi][r];
      }
  }
  __syncthreads();
  if (tid < 256) {
    float ma = pmL[tid], mb = pmL[256 + tid];
    float nm = fmaxf(ma, mb);
    float S = psL[tid] * __expf(ma - nm) + psL[256 + tid] * __expf(mb - nm);
    Pm[(size_t)by * NTOK + m0 + tid] = nm;   // coalesced: [by][token]
    Ps[(size_t)by * NTOK + m0 + tid] = S;
  }
}

// ---------------- combine 251 partials per token ----------------
__global__ void __launch_bounds__(256) loss_finalize_kernel(const float* __restrict__ Pm,
                                                            const float* __restrict__ Ps,
                                                            const float* __restrict__ scores,
                                                            const int* __restrict__ labels,
                                                            float* __restrict__ nll) {
  const int tok = blockIdx.x;
  float m = -1e30f, s = 0.f;
  for (int j = threadIdx.x; j < NBY; j += 256) {
    float m2 = Pm[(size_t)j * NTOK + tok], s2 = Ps[(size_t)j * NTOK + tok];
    float nm = fmaxf(m, m2);
    s = s * __expf(m - nm) + s2 * __expf(m2 - nm);
    m = nm;
  }
  for (int off = 32; off; off >>= 1) {
    float m2 = __shfl_down(m, off), s2 = __shfl_down(s, off);
    float nm = fmaxf(m, m2);
    s = s * __expf(m - nm) + s2 * __expf(m2 - nm);
    m = nm;
  }
  __shared__ float ms[4], sh[4];
  int wv = threadIdx.x >> 6, ln = threadIdx.x & 63;
  if (ln == 0) { ms[wv] = m; sh[wv] = s; }
  __syncthreads();
  if (threadIdx.x == 0) {
    float M = ms[0], S = sh[0];
    for (int i = 1; i < 4; ++i) {
      float nm = fmaxf(M, ms[i]);
      S = S * __expf(M - nm) + sh[i] * __expf(ms[i] - nm);
      M = nm;
    }
    int lab = labels[tok];
    float v = 0.f;
    if (lab != IGN) v = (M + logf(S)) - scores[(size_t)tok * VOC + lab];
    nll[tok] = v;
  }
}

__global__ void __launch_bounds__(256) reduce_kernel(const float* __restrict__ nll,
                                                     const int* __restrict__ labels,
                                                     float* __restrict__ out) {
  float s = 0.f, c = 0.f;
  for (int i = threadIdx.x; i < NTOK; i += 256) {
    s += nll[i];
    c += (labels[i] != IGN) ? 1.0f : 0.0f;
  }
  for (int off = 32; off; off >>= 1) { s += __shfl_down(s, off); c += __shfl_down(c, off); }
  __shared__ float rs[4], rc[4];
  int wv = threadIdx.x >> 6, ln = threadIdx.x & 63;
  if (ln == 0) { rs[wv] = s; rc[wv] = c; }
  __syncthreads();
  if (threadIdx.x == 0) {
    float S = rs[0] + rs[1] + rs[2] + rs[3];
    float Cc = rc[0] + rc[1] + rc[2] + rc[3];
    out[0] = S / fmaxf(Cc, 1.0f);
  }
}

extern "C" void kernel_launch(void* const* d_in, const int* in_sizes, int n_in,
                              void* d_out, int out_size, void* d_ws, size_t ws_size,
                              hipStream_t stream) {
  const float* hs     = (const float*)d_in[0];  // [4,512,768] f32
  const int*   labels = (const int*)d_in[1];    // [4,512] i32
  const float* lnw    = (const float*)d_in[2];  // [768] f32
  const float* W      = (const float*)d_in[3];  // [32128,768] f32

  float* out    = (float*)d_out;
  float* scores = out + 1;                      // [2048,32128] f32

  char* ws = (char*)d_ws;
  unsigned short* Wb = (unsigned short*)ws;                 ws += (size_t)VOC * DM * 2;   // 49.3 MB
  unsigned short* Hb = (unsigned short*)ws;                 ws += (size_t)NTOK * DM * 2;  // 3.1 MB
  float* Pm          = (float*)ws;                          ws += (size_t)NBY * NTOK * 4; // 2.06 MB
  float* Ps          = (float*)ws;                          ws += (size_t)NBY * NTOK * 4; // 2.06 MB
  float* nll         = (float*)ws;

  cvt_w_kernel<<<(VOC * DM / 4) / 256, 256, 0, stream>>>(W, Wb);
  rmsnorm_kernel<<<NTOK, 256, 0, stream>>>(hs, lnw, Hb);
  gemm_kernel<<<8 * NBY, 512, 0, stream>>>(Hb, Wb, scores, Pm, Ps);
  loss_finalize_kernel<<<NTOK, 256, 0, stream>>>(Pm, Ps, scores, labels, nll);
  reduce_kernel<<<1, 256, 0, stream>>>(nll, labels, out);
}